// Round 1
// 414.034 us; speedup vs baseline: 1.1390x; 1.1390x over previous
//
#include <hip/hip_runtime.h>
#include <hip/hip_bf16.h>

#define N_NODES  50000
#define N_EDGES  800000
#define N_GRAPHS 64
#define CAP      64    // bucket capacity per node; Poisson(16) max deg ~45 << 64

typedef __bf16 bf16;
typedef __attribute__((ext_vector_type(8))) __bf16 bf16x8;
typedef __attribute__((ext_vector_type(4))) float f32x4;

#define MT 64          // rows (nodes) per block in the MLP kernel
#define HP 264         // padded LDS row length in bf16 (256 + 8 pad)

// ---------------------------------------------------------------------------
// Weight transpose + downconvert + count zeroing (folds the old memset).
// w[k][n] fp32 (k-major) -> wT[n][k] bf16. 640 blocks x 256 = 163840 threads.
// ---------------------------------------------------------------------------
__global__ void transpose_w(const float* __restrict__ w1, const float* __restrict__ w2,
                            const float* __restrict__ w3,
                            bf16* __restrict__ wT1, bf16* __restrict__ wT2,
                            bf16* __restrict__ wT3, int* __restrict__ count) {
    int i = blockIdx.x * 256 + threadIdx.x;
    if (i < 50304) count[i] = 0;           // zero counters (bucket launches after)
    if (i < 65536) {                       // w1: 256x256
        int n = i >> 8, k = i & 255;
        wT1[n * 256 + k] = (bf16)w1[k * 256 + n];
    } else if (i < 131072) {               // w2: 256x256
        int j = i - 65536;
        int n = j >> 8, k = j & 255;
        wT2[n * 256 + k] = (bf16)w2[k * 256 + n];
    } else if (i < 163840) {               // w3: 256x128
        int j = i - 131072;
        int n = j >> 8, k = j & 255;       // n in [0,128)
        wT3[n * 256 + k] = (bf16)w3[k * 128 + n];
    }
}

// ---------------------------------------------------------------------------
// Bucketing: the atomic IS the cursor. 800k int atomics (vs 51.2M fp32 in the
// naive scatter = L2 atomic-rate roofline at 168us). No scan, no permute.
// ---------------------------------------------------------------------------
__global__ __launch_bounds__(256) void bucket_kernel(const int* __restrict__ col,
                                                     int* __restrict__ count,
                                                     int* __restrict__ bucket) {
    int e = blockIdx.x * 256 + threadIdx.x;
    if (e < N_EDGES) {
        int c = col[e];
        int p = atomicAdd(&count[c], 1);
        if (p < CAP) bucket[(size_t)c * CAP + p] = e;   // clamp: OOB-safe
    }
}

// One wave per node; lane = feature. eid list = ONE coalesced 256B load,
// broadcast via shfl; each edge row = one coalesced 256B gather. Zero atomics.
// 8 loads always in flight: last iteration is predicated with a clamped index
// (duplicate loads of edge deg-1 hit the same cache line => ~free), so there
// is NO serial dependent-latency tail.
__global__ __launch_bounds__(256) void aggregate_kernel(const float* __restrict__ ea,
                                                        const int* __restrict__ count,
                                                        const int* __restrict__ bucket,
                                                        bf16* __restrict__ agg) {
    int node = (blockIdx.x * 256 + threadIdx.x) >> 6;
    int lane = threadIdx.x & 63;
    if (node >= N_NODES) return;
    int deg = count[node];
    deg = (deg > CAP) ? CAP : deg;
    int eid_l = bucket[(size_t)node * CAP + lane];   // lane p holds eid p (CAP==64)

    float a0 = 0.f, a1 = 0.f, a2 = 0.f, a3 = 0.f;
    float a4 = 0.f, a5 = 0.f, a6 = 0.f, a7 = 0.f;
    int iters = (deg + 7) >> 3;
    for (int it = 0; it < iters; ++it) {
        int j = it * 8;
#define GATHER(K, AK)                                                          \
        {                                                                      \
            int idx = j + K;                                                   \
            int src = (idx < deg) ? idx : (deg - 1);                           \
            int e   = __shfl(eid_l, src);                                      \
            float v = __builtin_nontemporal_load(ea + (size_t)e * 64 + lane);  \
            AK += (idx < deg) ? v : 0.f;                                       \
        }
        GATHER(0, a0) GATHER(1, a1) GATHER(2, a2) GATHER(3, a3)
        GATHER(4, a4) GATHER(5, a5) GATHER(6, a6) GATHER(7, a7)
#undef GATHER
    }
    float s = ((a0 + a1) + (a2 + a3)) + ((a4 + a5) + (a6 + a7));
    agg[(size_t)node * 64 + lane] = (bf16)s;
}

// ---------------------------------------------------------------------------
// GEMM layer for N=256 (layers 1 & 2): h(64x256) @ wT(256x256) -> h (in place).
// Single LDS buffer: accumulators live in registers across the internal
// barrier; all waves finish READING hin before anyone WRITES hout (same array).
// ---------------------------------------------------------------------------
template <bool LEAKY>
__device__ __forceinline__ void gemm256(bf16 (*h)[HP],
                                        const bf16* __restrict__ wT,
                                        const float* __restrict__ bias) {
    const int lane = threadIdx.x & 63;
    const int wave = threadIdx.x >> 6;
    const int lr = lane & 15;   // A: m, B: n, C/D: col
    const int lq = lane >> 4;   // quad
    const int n0 = wave * 64;

    f32x4 acc[4][4];
#pragma unroll
    for (int a = 0; a < 4; a++)
#pragma unroll
        for (int b = 0; b < 4; b++) acc[a][b] = (f32x4)(0.f);

#pragma unroll
    for (int k0 = 0; k0 < 256; k0 += 32) {
        bf16x8 afrag[4], bfrag[4];
#pragma unroll
        for (int mt = 0; mt < 4; mt++)
            afrag[mt] = __builtin_bit_cast(bf16x8,
                *(const uint4*)&h[mt * 16 + lr][k0 + lq * 8]);
#pragma unroll
        for (int nt = 0; nt < 4; nt++)
            bfrag[nt] = __builtin_bit_cast(bf16x8,
                *(const uint4*)(wT + (size_t)(n0 + nt * 16 + lr) * 256 + k0 + lq * 8));
#pragma unroll
        for (int mt = 0; mt < 4; mt++)
#pragma unroll
            for (int nt = 0; nt < 4; nt++)
                acc[mt][nt] = __builtin_amdgcn_mfma_f32_16x16x32_bf16(
                    afrag[mt], bfrag[nt], acc[mt][nt], 0, 0, 0);
    }

    __syncthreads();   // all waves done reading h; safe to overwrite in place

    // C/D layout: col = lane&15, row = (lane>>4)*4 + i   [m89/m91 verified]
#pragma unroll
    for (int nt = 0; nt < 4; nt++) {
        int n = n0 + nt * 16 + lr;
        float bv = bias[n];
#pragma unroll
        for (int mt = 0; mt < 4; mt++) {
#pragma unroll
            for (int i = 0; i < 4; i++) {
                int row = mt * 16 + lq * 4 + i;
                float v = acc[mt][nt][i] + bv;
                if (LEAKY) v = (v >= 0.f) ? v : 0.01f * v;
                h[row][n] = (bf16)v;
            }
        }
    }
}

// ---------------------------------------------------------------------------
// Final layer: h(64x256) @ wT3(128x256 n-major) + b3 -> out (global, fp32)
// ---------------------------------------------------------------------------
__device__ __forceinline__ void gemm_out(const bf16 (*hin)[HP],
                                         const bf16* __restrict__ wT3,
                                         const float* __restrict__ b3,
                                         float* __restrict__ out, int r0) {
    const int lane = threadIdx.x & 63;
    const int wave = threadIdx.x >> 6;
    const int lr = lane & 15;
    const int lq = lane >> 4;
    const int n0 = wave * 32;

    f32x4 acc[4][2];
#pragma unroll
    for (int a = 0; a < 4; a++)
#pragma unroll
        for (int b = 0; b < 2; b++) acc[a][b] = (f32x4)(0.f);

#pragma unroll
    for (int k0 = 0; k0 < 256; k0 += 32) {
        bf16x8 afrag[4], bfrag[2];
#pragma unroll
        for (int mt = 0; mt < 4; mt++)
            afrag[mt] = __builtin_bit_cast(bf16x8,
                *(const uint4*)&hin[mt * 16 + lr][k0 + lq * 8]);
#pragma unroll
        for (int nt = 0; nt < 2; nt++)
            bfrag[nt] = __builtin_bit_cast(bf16x8,
                *(const uint4*)(wT3 + (size_t)(n0 + nt * 16 + lr) * 256 + k0 + lq * 8));
#pragma unroll
        for (int mt = 0; mt < 4; mt++)
#pragma unroll
            for (int nt = 0; nt < 2; nt++)
                acc[mt][nt] = __builtin_amdgcn_mfma_f32_16x16x32_bf16(
                    afrag[mt], bfrag[nt], acc[mt][nt], 0, 0, 0);
    }

#pragma unroll
    for (int nt = 0; nt < 2; nt++) {
        int n = n0 + nt * 16 + lr;
        float bv = b3[n];
#pragma unroll
        for (int mt = 0; mt < 4; mt++) {
#pragma unroll
            for (int i = 0; i < 4; i++) {
                int row = mt * 16 + lq * 4 + i;
                int r = r0 + row;
                if (r < N_NODES) {
                    __builtin_nontemporal_store(acc[mt][nt][i] + bv,
                                                &out[(size_t)r * 128 + n]);
                }
            }
        }
    }
}

// ---------------------------------------------------------------------------
// Fused MLP: build h = [x | agg | u[batch]] (bf16) in ONE LDS buffer (33.8 KB
// -> 4 blocks/CU, was 2), then 3 GEMMs in place.
// ---------------------------------------------------------------------------
__global__ __launch_bounds__(256, 4) void mlp_kernel(
    const float* __restrict__ x, const bf16* __restrict__ agg,
    const float* __restrict__ u, const int* __restrict__ batch,
    const bf16* __restrict__ wT1, const float* __restrict__ b1,
    const bf16* __restrict__ wT2, const float* __restrict__ b2,
    const bf16* __restrict__ wT3, const float* __restrict__ b3,
    float* __restrict__ out) {
    __shared__ bf16 H[MT][HP];

    const int tid = threadIdx.x;
    const int r0 = blockIdx.x * MT;

    // x part: 64 rows x 32 chunks of 4 floats -> bf16
    for (int i = tid; i < MT * 32; i += 256) {
        int row = i >> 5, c4 = (i & 31) * 4;
        int r = r0 + row;
        float4 v = make_float4(0.f, 0.f, 0.f, 0.f);
        if (r < N_NODES) v = *(const float4*)(x + (size_t)r * 128 + c4);
        bf16* dst = &H[row][c4];
        dst[0] = (bf16)v.x; dst[1] = (bf16)v.y; dst[2] = (bf16)v.z; dst[3] = (bf16)v.w;
    }
    // agg part (already bf16): 64 rows x 8 chunks of 8 bf16
    for (int i = tid; i < MT * 8; i += 256) {
        int row = i >> 3, c8 = (i & 7) * 8;
        int r = r0 + row;
        uint4 v = make_uint4(0, 0, 0, 0);
        if (r < N_NODES) v = *(const uint4*)(agg + (size_t)r * 64 + c8);
        *(uint4*)&H[row][128 + c8] = v;
    }
    // u[batch] part: 64 rows x 16 chunks of 4 floats -> bf16
    for (int i = tid; i < MT * 16; i += 256) {
        int row = i >> 4, c4 = (i & 15) * 4;
        int r = r0 + row;
        float4 v = make_float4(0.f, 0.f, 0.f, 0.f);
        if (r < N_NODES) {
            int g = batch[r];
            v = *(const float4*)(u + g * 64 + c4);
        }
        bf16* dst = &H[row][192 + c4];
        dst[0] = (bf16)v.x; dst[1] = (bf16)v.y; dst[2] = (bf16)v.z; dst[3] = (bf16)v.w;
    }
    __syncthreads();

    gemm256<true>(H, wT1, b1);   // internal barrier between read and write
    __syncthreads();
    gemm256<true>(H, wT2, b2);
    __syncthreads();
    gemm_out(H, wT3, b3, out, r0);
}

// ---------------------------------------------------------------------------
extern "C" void kernel_launch(void* const* d_in, const int* in_sizes, int n_in,
                              void* d_out, int out_size, void* d_ws, size_t ws_size,
                              hipStream_t stream) {
    const float* x          = (const float*)d_in[0];
    const int*   edge_index = (const int*)d_in[1];
    const float* edge_attr  = (const float*)d_in[2];
    const float* u          = (const float*)d_in[3];
    const int*   batch      = (const int*)d_in[4];
    const float* w1         = (const float*)d_in[5];
    const float* b1         = (const float*)d_in[6];
    const float* w2         = (const float*)d_in[7];
    const float* b2         = (const float*)d_in[8];
    const float* w3         = (const float*)d_in[9];
    const float* b3         = (const float*)d_in[10];
    float* out = (float*)d_out;
    const int* col = edge_index + N_EDGES;   // row 1 of (2, E) int32

    // Workspace layout (aligned blocks):
    char* p = (char*)d_ws;
    int* count  = (int*)p;      p += 50304 * sizeof(int);                    // zeroed by transpose_w
    int* bucket = (int*)p;      p += (size_t)N_NODES * CAP * sizeof(int);    // 12.8 MB
    bf16* agg   = (bf16*)p;     p += (size_t)N_NODES * 64 * sizeof(bf16);    // 6.4 MB
    bf16* wT1   = (bf16*)p;     p += 256 * 256 * sizeof(bf16);
    bf16* wT2   = (bf16*)p;     p += 256 * 256 * sizeof(bf16);
    bf16* wT3   = (bf16*)p;

    transpose_w<<<640, 256, 0, stream>>>(w1, w2, w3, wT1, wT2, wT3, count);

    bucket_kernel<<<(N_EDGES + 255) / 256, 256, 0, stream>>>(col, count, bucket);

    aggregate_kernel<<<(N_NODES * 64 + 255) / 256, 256, 0, stream>>>(
        edge_attr, count, bucket, agg);

    mlp_kernel<<<(N_NODES + MT - 1) / MT, 256, 0, stream>>>(
        x, agg, u, batch, wT1, b1, wT2, b2, wT3, b3, out);
}